// Round 2
// baseline (10.972 us; speedup 1.0000x reference)
//
#include <hip/hip_runtime.h>

#define BATCH 16384
#define DIM 128

__global__ __launch_bounds__(256) void cc_kernel(
    const float* __restrict__ v, const float* __restrict__ e,
    const float* __restrict__ w_vv, const float* __restrict__ w_ev,
    const float* __restrict__ w_ve, const float* __restrict__ w_ee,
    const float* __restrict__ bias_v, const float* __restrict__ bias_e,
    float* __restrict__ v_out, float* __restrict__ e_out)
{
    const int tid = blockIdx.x * blockDim.x + threadIdx.x;
    const int row = tid >> 4;          // 16 lanes per row
    const int sub = tid & 15;
    const int col = sub << 2;          // first float4 at col, second at col+64

    const size_t off  = (size_t)row * DIM + col;
    const size_t off2 = off + 64;

    // issue all global loads up front for max MLP
    const float4 vr0 = *reinterpret_cast<const float4*>(v + off);
    const float4 vr1 = *reinterpret_cast<const float4*>(v + off2);
    const float4 er0 = *reinterpret_cast<const float4*>(e + off);
    const float4 er1 = *reinterpret_cast<const float4*>(e + off2);

    const float4 wvv0 = *reinterpret_cast<const float4*>(w_vv + col);
    const float4 wvv1 = *reinterpret_cast<const float4*>(w_vv + col + 64);
    const float4 wev0 = *reinterpret_cast<const float4*>(w_ev + col);
    const float4 wev1 = *reinterpret_cast<const float4*>(w_ev + col + 64);
    const float4 wve0 = *reinterpret_cast<const float4*>(w_ve + col);
    const float4 wve1 = *reinterpret_cast<const float4*>(w_ve + col + 64);
    const float4 wee0 = *reinterpret_cast<const float4*>(w_ee + col);
    const float4 wee1 = *reinterpret_cast<const float4*>(w_ee + col + 64);

    // partial dots: dvv = e.w_vv, dev = v.w_ev, dve = e.w_ve, dee = v.w_ee
    float dvv = er0.x*wvv0.x + er0.y*wvv0.y + er0.z*wvv0.z + er0.w*wvv0.w
              + er1.x*wvv1.x + er1.y*wvv1.y + er1.z*wvv1.z + er1.w*wvv1.w;
    float dev = vr0.x*wev0.x + vr0.y*wev0.y + vr0.z*wev0.z + vr0.w*wev0.w
              + vr1.x*wev1.x + vr1.y*wev1.y + vr1.z*wev1.z + vr1.w*wev1.w;
    float dve = er0.x*wve0.x + er0.y*wve0.y + er0.z*wve0.z + er0.w*wve0.w
              + er1.x*wve1.x + er1.y*wve1.y + er1.z*wve1.z + er1.w*wve1.w;
    float dee = vr0.x*wee0.x + vr0.y*wee0.y + vr0.z*wee0.z + vr0.w*wee0.w
              + vr1.x*wee1.x + vr1.y*wee1.y + vr1.z*wee1.z + vr1.w*wee1.w;

    // butterfly all-reduce across the 16-lane group (xor masks stay in-group)
    #pragma unroll
    for (int m = 1; m < 16; m <<= 1) {
        dvv += __shfl_xor(dvv, m, 64);
        dev += __shfl_xor(dev, m, 64);
        dve += __shfl_xor(dve, m, 64);
        dee += __shfl_xor(dee, m, 64);
    }

    const float4 bv0 = *reinterpret_cast<const float4*>(bias_v + col);
    const float4 bv1 = *reinterpret_cast<const float4*>(bias_v + col + 64);
    const float4 be0 = *reinterpret_cast<const float4*>(bias_e + col);
    const float4 be1 = *reinterpret_cast<const float4*>(bias_e + col + 64);

    float4 o;
    o.x = vr0.x*dvv + er0.x*dev + bv0.x;
    o.y = vr0.y*dvv + er0.y*dev + bv0.y;
    o.z = vr0.z*dvv + er0.z*dev + bv0.z;
    o.w = vr0.w*dvv + er0.w*dev + bv0.w;
    *reinterpret_cast<float4*>(v_out + off) = o;

    o.x = vr1.x*dvv + er1.x*dev + bv1.x;
    o.y = vr1.y*dvv + er1.y*dev + bv1.y;
    o.z = vr1.z*dvv + er1.z*dev + bv1.z;
    o.w = vr1.w*dvv + er1.w*dev + bv1.w;
    *reinterpret_cast<float4*>(v_out + off2) = o;

    o.x = vr0.x*dve + er0.x*dee + be0.x;
    o.y = vr0.y*dve + er0.y*dee + be0.y;
    o.z = vr0.z*dve + er0.z*dee + be0.z;
    o.w = vr0.w*dve + er0.w*dee + be0.w;
    *reinterpret_cast<float4*>(e_out + off) = o;

    o.x = vr1.x*dve + er1.x*dee + be1.x;
    o.y = vr1.y*dve + er1.y*dee + be1.y;
    o.z = vr1.z*dve + er1.z*dee + be1.z;
    o.w = vr1.w*dve + er1.w*dee + be1.w;
    *reinterpret_cast<float4*>(e_out + off2) = o;
}

extern "C" void kernel_launch(void* const* d_in, const int* in_sizes, int n_in,
                              void* d_out, int out_size, void* d_ws, size_t ws_size,
                              hipStream_t stream) {
    const float* v    = (const float*)d_in[0];
    const float* e    = (const float*)d_in[1];
    const float* w_vv = (const float*)d_in[2];
    const float* w_ev = (const float*)d_in[3];
    const float* w_ve = (const float*)d_in[4];
    const float* w_ee = (const float*)d_in[5];
    const float* b_v  = (const float*)d_in[6];
    const float* b_e  = (const float*)d_in[7];

    float* v_out = (float*)d_out;
    float* e_out = (float*)d_out + (size_t)BATCH * DIM;

    const int threads = 256;
    const int total   = BATCH * 16;       // 16 lanes per row
    const int blocks  = total / threads;  // 1024

    cc_kernel<<<blocks, threads, 0, stream>>>(v, e, w_vv, w_ev, w_ve, w_ee,
                                              b_v, b_e, v_out, e_out);
}